// Round 9
// baseline (42.177 us; speedup 1.0000x reference)
//
#include <hip/hip_runtime.h>
#include <math.h>

// Problem constants (from reference)
#define NN      131072          // ROWS*COLS*P = 64*64*32
#define Q       10
#define T1      8
#define GRID    2048
#define BLOCK   256

// d_out layout (float32, concatenated in return order):
//   [0, 10)                         prediction
//   [10, 10 + N*Q*T1)               voter_in[0]   (10,485,760)
//   [10 + N*Q*T1, ... + 2*N*Q*T1)   votes         (20,971,520)
#define VIN0_OFF   10u
#define VIN0_SZ    (NN * Q * T1)            // 10485760
#define VOTES_OFF  (VIN0_OFF + VIN0_SZ)     // 10485770 (8B-aligned)
#define VOTES_SZ   (2u * NN * Q * T1)       // 20971520
#define E_F2       (VOTES_SZ / 2u)          // 10,485,760 float2s of votes
#define CHUNK2     (E_F2 / GRID)            // 5120 float2s per block (pass 2)

#define ROWS_T     (2u * NN * Q)            // 2,621,440 (s,i,q) rows
#define CHUNK1     (ROWS_T / GRID)          // 1280 rows per block = 5 iters * 256
#define MASK_WORDS (ROWS_T / 64u)           // 40960 u64

// d_ws layout: [0, 80KB) tallies u32[Q*GRID]; [81920, +327680) mask u64[MASK_WORDS]
#define TALLY_BYTES (Q * GRID * 4)

// ---------- Pass 1: read-only weight sweep -> vote bitmask + tally ----------
// One thread per (s,i,q) row. Consecutive lanes = consecutive rows, so the
// wave's 64 scattered 4B reads cover a contiguous 2 KB of weights; each block
// sweeps a contiguous 40 KB. Vote bits exit via one __ballot per wave-iter.
__global__ __launch_bounds__(BLOCK) void dtnn_pass1(
    const float* __restrict__ spikes,   // (N,)
    const float* __restrict__ weights,  // (2, N, Q, T1)
    unsigned long long* __restrict__ mask,  // (MASK_WORDS,)
    unsigned int* __restrict__ tallies)     // (Q, GRID)
{
    const unsigned int lane = threadIdx.x & 63u;
    const unsigned int wid  = threadIdx.x >> 6;   // 4 waves/block

    unsigned int acc = 0u;   // lane k (<10) accumulates tally for class k

    const unsigned int row_base = blockIdx.x * CHUNK1 + threadIdx.x;
    #pragma unroll 1
    for (unsigned int it = 0; it < CHUNK1 / BLOCK; ++it) {
        const unsigned int row = row_base + it * BLOCK;   // consecutive per wave, 64-aligned
        const unsigned int ri  = row / Q;
        const unsigned int q   = row - Q * ri;
        const unsigned int i   = ri & (NN - 1u);

        float v = spikes[i];
        if (v >= 7.0f && !isinf(v)) v = 7.0f;      // clamp finite >= tau_eff
        const int  tv    = (int)v;
        const bool valid = (v >= 0.0f) && (v < 8.0f) && ((float)tv == v);

        bool vote = false;
        if (valid) {                                // exec-masked scalar load
            vote = (weights[row * 8u + (unsigned)tv] >= 3.5f);
        }

        const unsigned long long m = __ballot(vote);
        if (lane == 0) mask[row >> 6] = m;          // wave's 64 rows = one u64

        #pragma unroll
        for (int k = 0; k < Q; ++k) {
            const unsigned long long mk = __ballot(vote && (q == (unsigned)k));
            if (lane == (unsigned)k) acc += (unsigned)__popcll(mk);
        }
    }

    __shared__ unsigned int lt[4 * Q];
    if (lane < Q) lt[wid * Q + lane] = acc;
    __syncthreads();
    if (threadIdx.x < Q) {
        tallies[threadIdx.x * GRID + blockIdx.x] =
            lt[threadIdx.x] + lt[Q + threadIdx.x] + lt[2 * Q + threadIdx.x] + lt[3 * Q + threadIdx.x];
    }
}

// ---------- Pass 2: pure write sweep (no weight reads) ----------
// R8's contiguous-chunk structure; votes/vin reconstructed from spikes (L2)
// and the vote bitmask (u64 shared by 256 consecutive threads -> broadcast).
__global__ __launch_bounds__(BLOCK) void dtnn_pass2(
    const float* __restrict__ spikes,
    const unsigned long long* __restrict__ mask,
    float* __restrict__ out)
{
    float2* __restrict__ votes2 = (float2*)(out + VOTES_OFF);
    float2* __restrict__ vin2   = (float2*)(out + VIN0_OFF);

    const unsigned int jbase = blockIdx.x * CHUNK2 + threadIdx.x;
    #pragma unroll 1
    for (unsigned int it = 0; it < CHUNK2 / BLOCK; ++it) {
        const unsigned int j    = jbase + it * BLOCK;
        const unsigned int r    = j >> 2;
        const unsigned int slot = j & 3u;
        const unsigned int ri   = r / Q;
        const unsigned int i    = ri & (NN - 1u);

        float v = spikes[i];
        if (v >= 7.0f && !isinf(v)) v = 7.0f;
        const float t0 = (float)(2u * slot);
        const bool  h0 = (v == t0);                 // exact one-hot (Inf -> all zero)
        const bool  h1 = (v == t0 + 1.0f);

        const bool bit = (mask[r >> 6] >> (r & 63u)) & 1ull;

        votes2[j] = make_float2((h0 && bit) ? 1.0f : 0.0f,
                                (h1 && bit) ? 1.0f : 0.0f);

        if (r < NN * Q) {                           // s == 0 (block-uniform)
            vin2[j] = make_float2(h0 ? 1.0f : 0.0f, h1 ? 1.0f : 0.0f);
        }
    }
}

// One wave per class: coalesced partial loads + shuffle reduction.
__global__ __launch_bounds__(64 * Q) void dtnn_pred(
    const unsigned int* __restrict__ tallies,  // (Q, GRID)
    float* __restrict__ out)
{
    const unsigned int lane = threadIdx.x & 63u;
    const unsigned int q    = threadIdx.x >> 6;    // 0..9

    unsigned int s = 0;
    #pragma unroll
    for (int it = 0; it < GRID / 64; ++it)
        s += tallies[q * GRID + it * 64 + lane];
    #pragma unroll
    for (int off = 32; off >= 1; off >>= 1)
        s += __shfl_down(s, off, 64);

    __shared__ unsigned int sums[Q];
    if (lane == 0) sums[q] = s;
    __syncthreads();

    if (threadIdx.x == 0) {
        unsigned int best = sums[0]; int bi = 0;
        #pragma unroll
        for (int k = 1; k < Q; ++k)
            if (sums[k] > best) { best = sums[k]; bi = k; }   // first-index tie-break
        #pragma unroll
        for (int k = 0; k < Q; ++k) out[k] = (k == bi) ? 1.0f : 0.0f;
    }
}

extern "C" void kernel_launch(void* const* d_in, const int* in_sizes, int n_in,
                              void* d_out, int out_size, void* d_ws, size_t ws_size,
                              hipStream_t stream) {
    const float* spikes  = (const float*)d_in[0];   // (64,64,32) float32
    const float* weights = (const float*)d_in[1];   // (2, N, Q, T1) float32
    float* out = (float*)d_out;
    unsigned int*       tallies = (unsigned int*)d_ws;
    unsigned long long* mask    = (unsigned long long*)((char*)d_ws + TALLY_BYTES);

    dtnn_pass1<<<GRID, BLOCK, 0, stream>>>(spikes, weights, mask, tallies);
    dtnn_pass2<<<GRID, BLOCK, 0, stream>>>(spikes, mask, out);
    dtnn_pred<<<1, 64 * Q, 0, stream>>>(tallies, out);
}

// Round 10
// 41.819 us; speedup vs baseline: 1.0085x; 1.0085x over previous
//
#include <hip/hip_runtime.h>
#include <math.h>

// Problem constants (from reference)
#define NN      131072u         // ROWS*COLS*P = 64*64*32
#define Q       10
#define T1      8
#define GRID    2048
#define BLOCK   256

// d_out layout (float32, concatenated in return order):
//   [0, 10)                         prediction
//   [10, 10 + N*Q*T1)               voter_in[0]   (10,485,760)
//   [10 + N*Q*T1, ... + 2*N*Q*T1)   votes         (20,971,520)
#define VIN0_OFF   10u
#define VIN0_SZ    (NN * Q * T1)            // 10,485,760 floats
#define VOTES_OFF  (VIN0_OFF + VIN0_SZ)     // byte offset 8 mod 16 -> shift +2 floats for float4
#define VOTES_SZ   (2u * NN * Q * T1)       // 20,971,520 floats
#define ROWS_T     (2u * NN * Q)            // 2,621,440 (s,i,q) rows of 8 bins

// float4 body spaces (shifted +2 floats so stores are 16B-aligned):
//   votes body: floats [2, VOTES_SZ-2) -> 5,242,879 float4s; head {0,1}, tail {last 2}
//   vin   body: floats [2, VIN0_SZ-2)  -> 2,621,439 float4s; head {0,1}, tail {last 2}
#define VBODY_N    ((VOTES_SZ - 4u) / 4u)   // 5,242,879
#define VINBODY_N  ((VIN0_SZ  - 4u) / 4u)   // 2,621,439
#define CH4        2560u                    // float4s per block; 2048*2560 = VBODY_N+1 (last thread skips)

__device__ __forceinline__ float clamp_spike(float v) {
    return (v >= 7.0f && !isinf(v)) ? 7.0f : v;   // clamp finite >= tau_eff; Inf passes
}

// Body float4 index b -> global float f = 4b+2 in votes/vin space.
// f&7 == 2: bins {2,3,4,5} of row f>>3.  f&7 == 6: bins {6,7} of row r, {0,1} of row r+1.
__global__ __launch_bounds__(BLOCK) void dtnn_main(
    const float* __restrict__ spikes,   // (N,)
    const float* __restrict__ weights,  // (2, N, Q, T1)
    float* __restrict__ out,
    unsigned int* __restrict__ tallies) // (Q, GRID)
{
    const unsigned int lane = threadIdx.x & 63u;
    const unsigned int wid  = threadIdx.x >> 6;   // 4 waves/block

    float4* __restrict__ votes4 = (float4*)(out + VOTES_OFF + 2u);
    float4* __restrict__ vin4   = (float4*)(out + VIN0_OFF + 2u);

    unsigned int acc = 0u;   // lane k (<10) accumulates tally for class k

    // ---- head/tail 2-float pieces, block 0 only. Lane k matches the row's class. ----
    if (blockIdx.x == 0) {
        if (threadIdx.x == 0) {            // votes+vin head = row 0 (q=0), bins {0,1}
            const float v = clamp_spike(spikes[0]);
            const bool h0 = (v == 0.0f), h1 = (v == 1.0f);
            bool vote = false;
            if (h0 | h1) vote = (weights[(unsigned)(int)v] >= 3.5f);
            ((float2*)(out + VOTES_OFF))[0] =
                make_float2((h0 && vote) ? 1.0f : 0.0f, (h1 && vote) ? 1.0f : 0.0f);
            ((float2*)(out + VIN0_OFF))[0] =
                make_float2(h0 ? 1.0f : 0.0f, h1 ? 1.0f : 0.0f);
            acc += vote ? 1u : 0u;         // class 0 == lane 0
        }
        if (threadIdx.x == 9) {            // votes tail = row ROWS_T-1 (q=9), bins {6,7}
            const unsigned rt = ROWS_T - 1u;
            const float v = clamp_spike(spikes[(rt / Q) & (NN - 1u)]);
            const bool h6 = (v == 6.0f), h7 = (v == 7.0f);
            bool vote = false;
            if (h6 | h7) vote = (weights[rt * 8u + (unsigned)(int)v] >= 3.5f);
            ((float2*)(out + VOTES_OFF + VOTES_SZ - 2u))[0] =
                make_float2((h6 && vote) ? 1.0f : 0.0f, (h7 && vote) ? 1.0f : 0.0f);
            acc += vote ? 1u : 0u;         // class 9 == lane 9
            // vin tail = row NN*Q-1, bins {6,7} (write-only; its vote is tallied in body)
            const unsigned rv = NN * Q - 1u;
            const float v2 = clamp_spike(spikes[(rv / Q) & (NN - 1u)]);
            ((float2*)(out + VIN0_OFF + VIN0_SZ - 2u))[0] =
                make_float2((v2 == 6.0f) ? 1.0f : 0.0f, (v2 == 7.0f) ? 1.0f : 0.0f);
        }
    }

    // ---- contiguous per-block float4 body (R8's proven chunking) ----
    const unsigned int jb = blockIdx.x * CH4 + threadIdx.x;
    #pragma unroll 1
    for (unsigned int it = 0; it < CH4 / BLOCK; ++it) {
        const unsigned int b = jb + it * BLOCK;
        bool inc1 = false, inc2 = false;
        unsigned int qa = 0u, qb = 0u;
        if (b < VBODY_N) {                 // only global-last thread ever fails this
            const unsigned int f  = 4u * b + 2u;
            const unsigned int r  = f >> 3;
            const unsigned int ri = r / Q;
            const unsigned int q  = r - Q * ri;
            const unsigned int i  = ri & (NN - 1u);
            const float v = clamp_spike(spikes[i]);
            float4 vo, vi_;
            qa = q;
            if ((f & 4u) == 0u) {
                // bins {2,3,4,5} of row r
                const bool h2 = (v == 2.0f), h3 = (v == 3.0f), h4 = (v == 4.0f), h5 = (v == 5.0f);
                bool vote = false;
                if (h2 | h3 | h4 | h5) vote = (weights[r * 8u + (unsigned)(int)v] >= 3.5f);
                vi_ = make_float4(h2 ? 1.0f : 0.0f, h3 ? 1.0f : 0.0f,
                                  h4 ? 1.0f : 0.0f, h5 ? 1.0f : 0.0f);
                vo  = make_float4((h2 && vote) ? 1.0f : 0.0f, (h3 && vote) ? 1.0f : 0.0f,
                                  (h4 && vote) ? 1.0f : 0.0f, (h5 && vote) ? 1.0f : 0.0f);
                inc1 = vote;
            } else {
                // bins {6,7} of row r + bins {0,1} of row r+1
                const bool h6 = (v == 6.0f), h7 = (v == 7.0f);
                bool vote_a = false;
                if (h6 | h7) vote_a = (weights[r * 8u + (unsigned)(int)v] >= 3.5f);
                const bool wrap = (q == (unsigned)(Q - 1));
                qb = wrap ? 0u : (q + 1u);
                const unsigned int i1 = (ri + (wrap ? 1u : 0u)) & (NN - 1u);
                const float v1 = clamp_spike(spikes[i1]);
                const bool g0 = (v1 == 0.0f), g1 = (v1 == 1.0f);
                bool vote_b = false;
                if (g0 | g1) vote_b = (weights[(r + 1u) * 8u + (unsigned)(int)v1] >= 3.5f);
                vi_ = make_float4(h6 ? 1.0f : 0.0f, h7 ? 1.0f : 0.0f,
                                  g0 ? 1.0f : 0.0f, g1 ? 1.0f : 0.0f);
                vo  = make_float4((h6 && vote_a) ? 1.0f : 0.0f, (h7 && vote_a) ? 1.0f : 0.0f,
                                  (g0 && vote_b) ? 1.0f : 0.0f, (g1 && vote_b) ? 1.0f : 0.0f);
                inc1 = vote_a; inc2 = vote_b;
            }
            votes4[b] = vo;                          // 16B-aligned dwordx4 store
            if (b < VINBODY_N) vin4[b] = vi_;        // block-contiguous predicate
        }
        // Wave-level tally: a straddle thread may contribute to two classes.
        #pragma unroll
        for (int k = 0; k < Q; ++k) {
            const unsigned long long m =
                __ballot((inc1 && qa == (unsigned)k) || (inc2 && qb == (unsigned)k));
            if (lane == (unsigned)k) acc += (unsigned)__popcll(m);
        }
    }

    // Combine 4 waves' lane-resident tallies via plain LDS stores.
    __shared__ unsigned int lt[4 * Q];
    if (lane < Q) lt[wid * Q + lane] = acc;
    __syncthreads();
    if (threadIdx.x < Q) {
        tallies[threadIdx.x * GRID + blockIdx.x] =
            lt[threadIdx.x] + lt[Q + threadIdx.x] + lt[2 * Q + threadIdx.x] + lt[3 * Q + threadIdx.x];
    }
}

// One wave per class: coalesced partial loads + shuffle reduction.
__global__ __launch_bounds__(64 * Q) void dtnn_pred(
    const unsigned int* __restrict__ tallies,  // (Q, GRID)
    float* __restrict__ out)
{
    const unsigned int lane = threadIdx.x & 63u;
    const unsigned int q    = threadIdx.x >> 6;    // 0..9

    unsigned int s = 0;
    #pragma unroll
    for (int it = 0; it < GRID / 64; ++it)
        s += tallies[q * GRID + it * 64 + lane];
    #pragma unroll
    for (int off = 32; off >= 1; off >>= 1)
        s += __shfl_down(s, off, 64);

    __shared__ unsigned int sums[Q];
    if (lane == 0) sums[q] = s;
    __syncthreads();

    if (threadIdx.x == 0) {
        unsigned int best = sums[0]; int bi = 0;
        #pragma unroll
        for (int k = 1; k < Q; ++k)
            if (sums[k] > best) { best = sums[k]; bi = k; }   // first-index tie-break
        #pragma unroll
        for (int k = 0; k < Q; ++k) out[k] = (k == bi) ? 1.0f : 0.0f;
    }
}

extern "C" void kernel_launch(void* const* d_in, const int* in_sizes, int n_in,
                              void* d_out, int out_size, void* d_ws, size_t ws_size,
                              hipStream_t stream) {
    const float* spikes  = (const float*)d_in[0];   // (64,64,32) float32
    const float* weights = (const float*)d_in[1];   // (2, N, Q, T1) float32
    float* out = (float*)d_out;
    unsigned int* tallies = (unsigned int*)d_ws;    // Q * GRID uints = 80 KB

    dtnn_main<<<GRID, BLOCK, 0, stream>>>(spikes, weights, out, tallies);
    dtnn_pred<<<1, 64 * Q, 0, stream>>>(tallies, out);
}